// Round 2
// baseline (1188.601 us; speedup 1.0000x reference)
//
#include <hip/hip_runtime.h>
#include <hip/hip_bf16.h>
#include <math.h>

typedef short s8v __attribute__((ext_vector_type(8)));
typedef short s4v __attribute__((ext_vector_type(4)));
typedef __bf16 bf8v __attribute__((ext_vector_type(8)));
typedef float f4v __attribute__((ext_vector_type(4)));

#define GLOBAL_AS __attribute__((address_space(1)))
#define LDS_AS __attribute__((address_space(3)))

static __device__ __forceinline__ float bf2f(ushort u) {
  return __builtin_bit_cast(float, (unsigned int)u << 16);
}
static __device__ __forceinline__ ushort f2bf(float f) {
  unsigned int u = __builtin_bit_cast(unsigned int, f);
  u += 0x7FFFu + ((u >> 16) & 1u);
  return (ushort)(u >> 16);
}
static __device__ __forceinline__ float gelu_f(float v) {
  return 0.5f * v * (1.0f + erff(v * 0.70710678118654752f));
}
static __device__ __forceinline__ float wave_max_f(float v) {
  #pragma unroll
  for (int o = 32; o >= 1; o >>= 1) v = fmaxf(v, __shfl_xor(v, o));
  return v;
}
static __device__ __forceinline__ float wave_sum_f(float v) {
  #pragma unroll
  for (int o = 32; o >= 1; o >>= 1) v += __shfl_xor(v, o);
  return v;
}
static __device__ __forceinline__ void gload16(const ushort* g, const ushort* l) {
  __builtin_amdgcn_global_load_lds(
      (const GLOBAL_AS unsigned int*)g,
      (LDS_AS unsigned int*)l, 16, 0, 0);
}

// ---------------- weight fp32 -> bf16 convert ----------------
__global__ void cvt_f32_bf16(const float* __restrict__ in, ushort* __restrict__ out, int n) {
  int i = (blockIdx.x * 256 + threadIdx.x) * 4;
  if (i >= n) return;
  float4 v = *(const float4*)(in + i);
  s4v o;
  o[0] = (short)f2bf(v.x); o[1] = (short)f2bf(v.y);
  o[2] = (short)f2bf(v.z); o[3] = (short)f2bf(v.w);
  *(s4v*)(out + i) = o;
}

// ---------------- concat qkv biases ----------------
__global__ void concat_bias(const float* __restrict__ bq, const float* __restrict__ bk,
                            const float* __restrict__ bv, float* __restrict__ o) {
  int i = blockIdx.x * 256 + threadIdx.x;
  if (i < 512) o[i] = bq[i];
  else if (i < 1024) o[i] = bk[i - 512];
  else if (i < 1536) o[i] = bv[i - 1024];
}

// ---------------- batched Wo bias: bo2[b][n] = bo[n] + gv[b]·Wo[n,:] -------
__global__ __launch_bounds__(256) void bias_gv(
    const float* __restrict__ gv, const float* __restrict__ Wo,
    const float* __restrict__ bo, float* __restrict__ bo2) {
  const int b = blockIdx.x;
  const int n = blockIdx.y * 256 + threadIdx.x;
  const float* g = gv + b * 512;
  const float* w = Wo + (long)n * 512;
  float acc = 0.f;
  for (int d = 0; d < 512; d += 4) {
    float4 wv4 = *(const float4*)(w + d);
    acc += g[d] * wv4.x + g[d + 1] * wv4.y + g[d + 2] * wv4.z + g[d + 3] * wv4.w;
  }
  bo2[b * 512 + n] = bo[n] + acc;
}

// ---------------- LayerNorm over D=512, one wave per row ----------------
__global__ __launch_bounds__(256) void ln_rows(
    const float* __restrict__ x, const float* __restrict__ gam,
    const float* __restrict__ bet, const float* __restrict__ mask,
    ushort* __restrict__ out)
{
  const int tid = threadIdx.x, lane = tid & 63, wv = tid >> 6;
  const long row = (long)blockIdx.x * 4 + wv;
  const float* xp = x + row * 512 + lane * 8;
  float4 a = *(const float4*)xp;
  float4 b = *(const float4*)(xp + 4);
  float s = a.x + a.y + a.z + a.w + b.x + b.y + b.z + b.w;
  float q = a.x*a.x + a.y*a.y + a.z*a.z + a.w*a.w
          + b.x*b.x + b.y*b.y + b.z*b.z + b.w*b.w;
  s = wave_sum_f(s); q = wave_sum_f(q);
  float m = s * (1.f / 512.f);
  float var = q * (1.f / 512.f) - m * m;
  float r = rsqrtf(var + 1e-5f);
  float mk = mask ? mask[row] : 1.f;
  const float* gp = gam + lane * 8;
  const float* bp = bet + lane * 8;
  float4 g0 = *(const float4*)gp, g1 = *(const float4*)(gp + 4);
  float4 c0 = *(const float4*)bp, c1 = *(const float4*)(bp + 4);
  s8v o;
  o[0] = (short)f2bf(((a.x - m) * r * g0.x + c0.x) * mk);
  o[1] = (short)f2bf(((a.y - m) * r * g0.y + c0.y) * mk);
  o[2] = (short)f2bf(((a.z - m) * r * g0.z + c0.z) * mk);
  o[3] = (short)f2bf(((a.w - m) * r * g0.w + c0.w) * mk);
  o[4] = (short)f2bf(((b.x - m) * r * g1.x + c1.x) * mk);
  o[5] = (short)f2bf(((b.y - m) * r * g1.y + c1.y) * mk);
  o[6] = (short)f2bf(((b.z - m) * r * g1.z + c1.z) * mk);
  o[7] = (short)f2bf(((b.w - m) * r * g1.w + c1.w) * mk);
  *(s8v*)(out + row * 512 + lane * 8) = o;
}

// ---------------- bf16 GEMM: C[M,N] = A[M,K] @ W[N,K]^T, fused epilogues ---
// EPI 0: out bf16 = v + bias
// EPI 2: out bf16 = gelu(v + bias)
// EPI 3: out f32  = (resid + gelu(v + bias)) * mask[row]
// EPI 4: out f32  = v + bias_batched[row>>13] + resid
#define BMT 128
#define BNT 128
#define BKT 64

template<int EPI>
__global__ __launch_bounds__(256, 2) void gemm_bt(
    const ushort* __restrict__ A, int lda,
    const ushort* __restrict__ W,
    const float* __restrict__ bias, const float* __restrict__ resid,
    const float* __restrict__ mask, void* __restrict__ Out, int ldc,
    int K, int nbx)
{
  __shared__ __align__(16) ushort lsA[BMT * BKT];
  __shared__ __align__(16) ushort lsB[BNT * BKT];
  const int tid = threadIdx.x;
  const int lane = tid & 63;
  const int wid = tid >> 6;
  const int wr = wid >> 1, wc = wid & 1;

  // chunked bijective XCD swizzle (nwg % 8 == 0 for all our launches)
  const int nwg = gridDim.x;
  const int cpx = nwg >> 3;
  const int hw = blockIdx.x;
  const int wg = (hw & 7) * cpx + (hw >> 3);
  const int bx = wg % nbx;
  const int by = wg / nbx;
  const long bm = (long)by * BMT;
  const int bn = bx * BNT;

  f4v acc[4][4] = {};

  // staging geometry: wave wid stages rows [p*32 + wid*8, +8), lane l covers
  // row +l/8, LDS col (l&7)*8; global source col pre-swizzled so the LDS
  // layout matches the XOR-swizzled read pattern.
  const int r8 = lane >> 3;                     // 0..7
  const int sc = ((lane & 7) * 8) ^ (r8 << 3);  // pre-swizzled col
  const ushort* ap[4];
  const ushort* bp[4];
  #pragma unroll
  for (int p = 0; p < 4; ++p) {
    const int row = p * 32 + wid * 8 + r8;
    ap[p] = A + (bm + row) * (long)lda + sc;
    bp[p] = W + (long)(bn + row) * K + sc;
  }

  for (int k0 = 0; k0 < K; k0 += BKT) {
    if (k0) __syncthreads();
    #pragma unroll
    for (int p = 0; p < 4; ++p) {
      gload16(ap[p] + k0, lsA + (p * 32 + wid * 8) * BKT);
      gload16(bp[p] + k0, lsB + (p * 32 + wid * 8) * BKT);
    }
    __syncthreads();
    #pragma unroll
    for (int kk = 0; kk < 2; ++kk) {
      const int kb = kk * 32 + (lane >> 4) * 8;
      bf8v af[4], bfr[4];
      #pragma unroll
      for (int m = 0; m < 4; ++m) {
        int row = wr * 64 + m * 16 + (lane & 15);
        af[m] = *(const bf8v*)(lsA + row * BKT + (kb ^ ((row & 7) << 3)));
      }
      #pragma unroll
      for (int n = 0; n < 4; ++n) {
        int row = wc * 64 + n * 16 + (lane & 15);
        bfr[n] = *(const bf8v*)(lsB + row * BKT + (kb ^ ((row & 7) << 3)));
      }
      #pragma unroll
      for (int m = 0; m < 4; ++m)
        #pragma unroll
        for (int n = 0; n < 4; ++n)
          acc[m][n] = __builtin_amdgcn_mfma_f32_16x16x32_bf16(af[m], bfr[n], acc[m][n], 0, 0, 0);
    }
  }

  const int colbase = bn + wc * 64 + (lane & 15);
  const long rowbase = bm + wr * 64 + ((lane >> 4) * 4);
  const float* biasp = (EPI == 4) ? bias + ((bm >> 13) << 9) : bias;
  #pragma unroll
  for (int m = 0; m < 4; ++m) {
    #pragma unroll
    for (int j = 0; j < 4; ++j) {
      const long row = rowbase + m * 16 + j;
      #pragma unroll
      for (int n = 0; n < 4; ++n) {
        const int col = colbase + n * 16;
        float v = acc[m][n][j] + biasp[col];
        const long idx = row * (long)ldc + col;
        if constexpr (EPI == 0) {
          ((ushort*)Out)[idx] = f2bf(v);
        } else if constexpr (EPI == 2) {
          ((ushort*)Out)[idx] = f2bf(gelu_f(v));
        } else if constexpr (EPI == 3) {
          ((float*)Out)[idx] = (resid[idx] + gelu_f(v)) * mask[row];
        } else {
          ((float*)Out)[idx] = v + resid[idx];
        }
      }
    }
  }
}

// ---------------- stage 1 pooling: softmax over N of Q·q_alpha, weighted Q sum
// Q base pointer already offset to the head-0 column; row stride 1536.
__global__ __launch_bounds__(1024) void pool_stage1(
    const ushort* __restrict__ Q, const float* __restrict__ qa,
    const float* __restrict__ mask, float* __restrict__ gq)
{
  __shared__ float sl[8192];
  __shared__ float red[16];
  __shared__ float sca[64];
  __shared__ float bcast;
  const int bh = blockIdx.x;
  const int b = bh >> 3, h = bh & 7;
  const int tid = threadIdx.x, lane = tid & 63, wv = tid >> 6;
  if (tid < 64) sca[tid] = qa[h * 64 + tid];
  __syncthreads();
  const float scale = 0.125f;
  float lmax = -INFINITY;
  for (int n = tid; n < 8192; n += 1024) {
    const ushort* qp = Q + ((long)(b * 8192 + n) * 1536 + h * 64);
    float dot = 0.f;
    #pragma unroll
    for (int c = 0; c < 8; ++c) {
      s8v v = *(const s8v*)(qp + c * 8);
      #pragma unroll
      for (int j = 0; j < 8; ++j) dot += bf2f((ushort)v[j]) * sca[c * 8 + j];
    }
    float lg = dot * scale;
    if (mask[b * 8192 + n] == 0.f) lg = -INFINITY;
    sl[n] = lg;
    lmax = fmaxf(lmax, lg);
  }
  lmax = wave_max_f(lmax);
  if (lane == 0) red[wv] = lmax;
  __syncthreads();
  if (tid < 64) {
    float v = (lane < 16) ? red[lane] : -INFINITY;
    v = wave_max_f(v);
    if (lane == 0) bcast = v;
  }
  __syncthreads();
  const float gmax = bcast;
  float lsum = 0.f;
  for (int n = tid; n < 8192; n += 1024) {
    float e = __expf(sl[n] - gmax);
    sl[n] = e;
    lsum += e;
  }
  lsum = wave_sum_f(lsum);
  __syncthreads();
  if (lane == 0) red[wv] = lsum;
  __syncthreads();
  if (tid < 64) {
    float v = (lane < 16) ? red[lane] : 0.f;
    v = wave_sum_f(v);
    if (lane == 0) bcast = v;
  }
  __syncthreads();
  const float S = bcast;
  float acc = 0.f;
  for (int n = wv; n < 8192; n += 16) {
    acc += sl[n] * bf2f(Q[(long)(b * 8192 + n) * 1536 + h * 64 + lane]);
  }
  __syncthreads();
  sl[wv * 64 + lane] = acc;
  __syncthreads();
  if (tid < 64) {
    float t = 0.f;
    #pragma unroll
    for (int w2 = 0; w2 < 16; ++w2) t += sl[w2 * 64 + tid];
    gq[bh * 64 + tid] = t / S;
  }
}

// ---------------- stage 2 pooling: softmax over N of (K*gq)·k_beta, weighted V sum
__global__ __launch_bounds__(1024) void pool_stage2(
    const ushort* __restrict__ Km, const ushort* __restrict__ Vm,
    const float* __restrict__ kb, const float* __restrict__ gq,
    const float* __restrict__ mask, float* __restrict__ gv)
{
  __shared__ float sl[8192];
  __shared__ float red[16];
  __shared__ float wvec[64];
  __shared__ float bcast;
  const int bh = blockIdx.x;
  const int b = bh >> 3, h = bh & 7;
  const int tid = threadIdx.x, lane = tid & 63, wv = tid >> 6;
  if (tid < 64) wvec[tid] = gq[bh * 64 + tid] * kb[h * 64 + tid];
  __syncthreads();
  const float scale = 0.125f;
  float lmax = -INFINITY;
  for (int n = tid; n < 8192; n += 1024) {
    const ushort* kp = Km + ((long)(b * 8192 + n) * 1536 + h * 64);
    float dot = 0.f;
    #pragma unroll
    for (int c = 0; c < 8; ++c) {
      s8v v = *(const s8v*)(kp + c * 8);
      #pragma unroll
      for (int j = 0; j < 8; ++j) dot += bf2f((ushort)v[j]) * wvec[c * 8 + j];
    }
    float lg = dot * scale;
    if (mask[b * 8192 + n] == 0.f) lg = -INFINITY;
    sl[n] = lg;
    lmax = fmaxf(lmax, lg);
  }
  lmax = wave_max_f(lmax);
  if (lane == 0) red[wv] = lmax;
  __syncthreads();
  if (tid < 64) {
    float v = (lane < 16) ? red[lane] : -INFINITY;
    v = wave_max_f(v);
    if (lane == 0) bcast = v;
  }
  __syncthreads();
  const float gmax = bcast;
  float lsum = 0.f;
  for (int n = tid; n < 8192; n += 1024) {
    float e = __expf(sl[n] - gmax);
    sl[n] = e;
    lsum += e;
  }
  lsum = wave_sum_f(lsum);
  __syncthreads();
  if (lane == 0) red[wv] = lsum;
  __syncthreads();
  if (tid < 64) {
    float v = (lane < 16) ? red[lane] : 0.f;
    v = wave_sum_f(v);
    if (lane == 0) bcast = v;
  }
  __syncthreads();
  const float S = bcast;
  float acc = 0.f;
  for (int n = wv; n < 8192; n += 16) {
    acc += sl[n] * bf2f(Vm[(long)(b * 8192 + n) * 1536 + h * 64 + lane]);
  }
  __syncthreads();
  sl[wv * 64 + lane] = acc;
  __syncthreads();
  if (tid < 64) {
    float t = 0.f;
    #pragma unroll
    for (int w2 = 0; w2 < 16; ++w2) t += sl[w2 * 64 + tid];
    gv[bh * 64 + tid] = t / S;
  }
}

// ---------------- host ----------------
extern "C" void kernel_launch(void* const* d_in, const int* in_sizes, int n_in,
                              void* d_out, int out_size, void* d_ws, size_t ws_size,
                              hipStream_t stream) {
  const float* x    = (const float*)d_in[0];
  const float* mask = (const float*)d_in[1];
  const float* Wq   = (const float*)d_in[2];
  const float* bq   = (const float*)d_in[3];
  const float* Wk   = (const float*)d_in[4];
  const float* bk   = (const float*)d_in[5];
  const float* Wv   = (const float*)d_in[6];
  const float* bv   = (const float*)d_in[7];
  const float* qa   = (const float*)d_in[8];
  const float* kb   = (const float*)d_in[9];
  const float* Wo   = (const float*)d_in[10];
  const float* bo   = (const float*)d_in[11];
  const float* g0   = (const float*)d_in[12];
  const float* be0  = (const float*)d_in[13];
  const float* g1   = (const float*)d_in[14];
  const float* be1  = (const float*)d_in[15];
  const float* W1   = (const float*)d_in[16];
  const float* b1   = (const float*)d_in[17];
  const float* W2   = (const float*)d_in[18];
  const float* b2   = (const float*)d_in[19];
  float* out = (float*)d_out;

  const int M = 65536;          // B*N
  char* ws = (char*)d_ws;
  const size_t MB = 1024 * 1024;
  // layout (lifetimes disjoint where overlapped):
  //   [0,64)    XN   : ln0 out -> QKV GEMM in; reused as ln1 out -> W1 in
  //   [64,256)  QKV  : bf16 [M,1536], dead after Wo GEMM
  //   [64,320)  H1   : bf16 [M,2048], written by W1 (after QKV dead)
  //   [320,448) X1   : f32 [M,512], Wo+resid out, ln1 in, W2 resid
  //   [448,...) smalls + bf16 weights
  ushort* XN  = (ushort*)(ws);
  ushort* QKV = (ushort*)(ws + 64 * MB);
  ushort* H1  = (ushort*)(ws + 64 * MB);
  float*  X1  = (float*)(ws + 320 * MB);
  char* small = ws + 448 * MB;
  float*  GQ  = (float*)(small);                 // 16KB
  float*  GV  = (float*)(small + 16 * 1024);     // 16KB
  float*  BO2 = (float*)(small + 32 * 1024);     // 16KB
  float*  BQKV= (float*)(small + 48 * 1024);     // 8KB
  ushort* WQKVB = (ushort*)(small + 64 * 1024);  // 1.5MB
  ushort* WOB = WQKVB + 3 * 262144;
  ushort* W1B = WOB + 262144;
  ushort* W2B = W1B + 1048576;

  // weight conversions + bias concat
  cvt_f32_bf16<<<256, 256, 0, stream>>>(Wq, WQKVB, 262144);
  cvt_f32_bf16<<<256, 256, 0, stream>>>(Wk, WQKVB + 262144, 262144);
  cvt_f32_bf16<<<256, 256, 0, stream>>>(Wv, WQKVB + 524288, 262144);
  cvt_f32_bf16<<<256, 256, 0, stream>>>(Wo, WOB, 262144);
  cvt_f32_bf16<<<1024, 256, 0, stream>>>(W1, W1B, 1048576);
  cvt_f32_bf16<<<1024, 256, 0, stream>>>(W2, W2B, 1048576);
  concat_bias<<<6, 256, 0, stream>>>(bq, bk, bv, BQKV);

  // LN0 (+mask)
  ln_rows<<<M / 4, 256, 0, stream>>>(x, g0, be0, mask, XN);

  // fused QKV GEMM: [M,512] @ [1536,512]^T -> [M,1536]
  gemm_bt<0><<<12 * (M / BMT), 256, 0, stream>>>(XN, 512, WQKVB, BQKV, nullptr, nullptr, QKV, 1536, 512, 12);

  // pooling (Q at col 0, K at col 512, V at col 1024; row stride 1536)
  pool_stage1<<<64, 1024, 0, stream>>>(QKV, qa, mask, GQ);
  pool_stage2<<<64, 1024, 0, stream>>>(QKV + 512, QKV + 1024, kb, GQ, mask, GV);

  // fold global_v into Wo bias: bo2[b] = bo + gv[b] @ Wo^T
  bias_gv<<<dim3(8, 2), 256, 0, stream>>>(GV, Wo, bo, BO2);

  // Wo GEMM + batched bias + residual -> X1 (f32); A = Q columns of QKV
  gemm_bt<4><<<4 * (M / BMT), 256, 0, stream>>>(QKV, 1536, WOB, BO2, x, nullptr, X1, 512, 512, 4);

  // LN1 -> XN (bf16)
  ln_rows<<<M / 4, 256, 0, stream>>>(X1, g1, be1, nullptr, XN);

  // MLP
  gemm_bt<2><<<16 * (M / BMT), 256, 0, stream>>>(XN, 512, W1B, b1, nullptr, nullptr, H1, 2048, 512, 16);
  gemm_bt<3><<<4 * (M / BMT), 256, 0, stream>>>(H1, 2048, W2B, b2, X1, mask, out, 512, 2048, 4);
}

// Round 3
// 1131.646 us; speedup vs baseline: 1.0503x; 1.0503x over previous
//
#include <hip/hip_runtime.h>
#include <hip/hip_bf16.h>
#include <math.h>

typedef short s8v __attribute__((ext_vector_type(8)));
typedef short s4v __attribute__((ext_vector_type(4)));
typedef __bf16 bf8v __attribute__((ext_vector_type(8)));
typedef float f4v __attribute__((ext_vector_type(4)));

#define GLOBAL_AS __attribute__((address_space(1)))
#define LDS_AS __attribute__((address_space(3)))

static __device__ __forceinline__ float bf2f(ushort u) {
  return __builtin_bit_cast(float, (unsigned int)u << 16);
}
static __device__ __forceinline__ ushort f2bf(float f) {
  unsigned int u = __builtin_bit_cast(unsigned int, f);
  u += 0x7FFFu + ((u >> 16) & 1u);
  return (ushort)(u >> 16);
}
// fast tanh-gelu: gelu(v) = v * sigmoid(2*0.79788456*(v + 0.044715 v^3))
static __device__ __forceinline__ float gelu_f(float v) {
  float t = v * v;
  float u = v * (0.0356774081f * t + 0.7978845608f);
  float e = __expf(-2.0f * u);
  return v / (1.0f + e);
}
static __device__ __forceinline__ float wave_max_f(float v) {
  #pragma unroll
  for (int o = 32; o >= 1; o >>= 1) v = fmaxf(v, __shfl_xor(v, o));
  return v;
}
static __device__ __forceinline__ float wave_sum_f(float v) {
  #pragma unroll
  for (int o = 32; o >= 1; o >>= 1) v += __shfl_xor(v, o);
  return v;
}
static __device__ __forceinline__ void gload16(const ushort* g, const ushort* l) {
  __builtin_amdgcn_global_load_lds(
      (const GLOBAL_AS unsigned int*)g,
      (LDS_AS unsigned int*)l, 16, 0, 0);
}

// ---------------- weight fp32 -> bf16 convert ----------------
__global__ void cvt_f32_bf16(const float* __restrict__ in, ushort* __restrict__ out, int n) {
  int i = (blockIdx.x * 256 + threadIdx.x) * 4;
  if (i >= n) return;
  float4 v = *(const float4*)(in + i);
  s4v o;
  o[0] = (short)f2bf(v.x); o[1] = (short)f2bf(v.y);
  o[2] = (short)f2bf(v.z); o[3] = (short)f2bf(v.w);
  *(s4v*)(out + i) = o;
}

// ---------------- concat qkv biases ----------------
__global__ void concat_bias(const float* __restrict__ bq, const float* __restrict__ bk,
                            const float* __restrict__ bv, float* __restrict__ o) {
  int i = blockIdx.x * 256 + threadIdx.x;
  if (i < 512) o[i] = bq[i];
  else if (i < 1024) o[i] = bk[i - 512];
  else if (i < 1536) o[i] = bv[i - 1024];
}

// ---------------- batched Wo bias: bo2[b][n] = bo[n] + gv[b]·Wo[n,:] -------
__global__ __launch_bounds__(256) void bias_gv(
    const float* __restrict__ gv, const float* __restrict__ Wo,
    const float* __restrict__ bo, float* __restrict__ bo2) {
  const int b = blockIdx.x;
  const int n = blockIdx.y * 256 + threadIdx.x;
  const float* g = gv + b * 512;
  const float* w = Wo + (long)n * 512;
  float acc = 0.f;
  for (int d = 0; d < 512; d += 4) {
    float4 wv4 = *(const float4*)(w + d);
    acc += g[d] * wv4.x + g[d + 1] * wv4.y + g[d + 2] * wv4.z + g[d + 3] * wv4.w;
  }
  bo2[b * 512 + n] = bo[n] + acc;
}

// ---------------- LayerNorm over D=512, one wave per row ----------------
__global__ __launch_bounds__(256) void ln_rows(
    const float* __restrict__ x, const float* __restrict__ gam,
    const float* __restrict__ bet, const float* __restrict__ mask,
    ushort* __restrict__ out)
{
  const int tid = threadIdx.x, lane = tid & 63, wv = tid >> 6;
  const long row = (long)blockIdx.x * 4 + wv;
  const float* xp = x + row * 512 + lane * 8;
  float4 a = *(const float4*)xp;
  float4 b = *(const float4*)(xp + 4);
  float s = a.x + a.y + a.z + a.w + b.x + b.y + b.z + b.w;
  float q = a.x*a.x + a.y*a.y + a.z*a.z + a.w*a.w
          + b.x*b.x + b.y*b.y + b.z*b.z + b.w*b.w;
  s = wave_sum_f(s); q = wave_sum_f(q);
  float m = s * (1.f / 512.f);
  float var = q * (1.f / 512.f) - m * m;
  float r = rsqrtf(var + 1e-5f);
  float mk = mask ? mask[row] : 1.f;
  const float* gp = gam + lane * 8;
  const float* bp = bet + lane * 8;
  float4 g0 = *(const float4*)gp, g1 = *(const float4*)(gp + 4);
  float4 c0 = *(const float4*)bp, c1 = *(const float4*)(bp + 4);
  s8v o;
  o[0] = (short)f2bf(((a.x - m) * r * g0.x + c0.x) * mk);
  o[1] = (short)f2bf(((a.y - m) * r * g0.y + c0.y) * mk);
  o[2] = (short)f2bf(((a.z - m) * r * g0.z + c0.z) * mk);
  o[3] = (short)f2bf(((a.w - m) * r * g0.w + c0.w) * mk);
  o[4] = (short)f2bf(((b.x - m) * r * g1.x + c1.x) * mk);
  o[5] = (short)f2bf(((b.y - m) * r * g1.y + c1.y) * mk);
  o[6] = (short)f2bf(((b.z - m) * r * g1.z + c1.z) * mk);
  o[7] = (short)f2bf(((b.w - m) * r * g1.w + c1.w) * mk);
  *(s8v*)(out + row * 512 + lane * 8) = o;
}

// ======== 256x256 pipelined bf16 GEMM: C = A[M,K] @ W[N,K]^T, fused epi ====
// 8 waves (2M x 4N), per-wave 128x64 C. BK=32, 4 LDS buffers (128KB),
// strictly barrier-ordered 3-deep prefetch, counted vmcnt(8), raw s_barrier,
// setprio around MFMA cluster.
// LDS tile layout (per buf, per matrix): 128 LDS-rows x 64 bf16; source rows
// (2R, 2R+1) packed into LDS-row R with 16B-slot permutation s = d ^ (R&7),
// d = 4*(row&1) + kunit. Staged via gload16 with pre-permuted global source.
// EPI 0: out bf16 = v + bias
// EPI 2: out bf16 = gelu(v + bias)
// EPI 3: out f32  = (resid + gelu(v + bias)) * mask[row]
// EPI 4: out f32  = v + bias_batched[row>>13] + resid
#define BM 256
#define BN 256
#define BK 32

template<int EPI>
__global__ __launch_bounds__(512, 2) void gemm256(
    const ushort* __restrict__ A, int lda,
    const ushort* __restrict__ W, int ldw,
    const float* __restrict__ bias, const float* __restrict__ resid,
    const float* __restrict__ mask, void* __restrict__ Out, int ldc,
    int K, int nbx)
{
  __shared__ __align__(16) ushort lds[4][2][8192];   // [buf][A=0/B=1][128*64]
  const int tid = threadIdx.x;
  const int lane = tid & 63;
  const int w = tid >> 6;        // wave 0..7
  const int wm = w >> 2;         // 0..1 (row group of 128)
  const int wn = w & 3;          // 0..3 (col group of 64)

  // chunked bijective XCD swizzle (all launches have nwg % 8 == 0)
  const int nwg = gridDim.x;
  const int cpx = nwg >> 3;
  const int wg = (blockIdx.x & 7) * cpx + (blockIdx.x >> 3);
  const int bx = wg % nbx, by = wg / nbx;
  const long bm = (long)by * BM;
  const int bn = bx * BN;

  // ---- staging source (per-lane permuted): unit u = w*64+lane (and +512)
  const int d = (lane & 7) ^ (lane >> 3);
  const int sr = 16 * w + 2 * (lane >> 3) + (d >> 2);   // 0..127
  const int koff = (d & 3) * 8;
  const ushort* a0 = A + (bm + sr) * (long)lda + koff;
  const ushort* a1 = A + (bm + sr + 128) * (long)lda + koff;
  const ushort* b0 = W + (long)(bn + sr) * ldw + koff;
  const ushort* b1 = W + (long)(bn + sr + 128) * ldw + koff;
  const int NT = K / BK;

#define STAGE(tt) { \
    const int kk0 = (tt) * BK; \
    ushort* La_ = &lds[(tt) & 3][0][0]; \
    ushort* Lb_ = &lds[(tt) & 3][1][0]; \
    gload16(a0 + kk0, La_ + w * 512); \
    gload16(a1 + kk0, La_ + 4096 + w * 512); \
    gload16(b0 + kk0, Lb_ + w * 512); \
    gload16(b1 + kk0, Lb_ + 4096 + w * 512); \
  }

  STAGE(0); STAGE(1); STAGE(2);

  f4v acc[8][4] = {};

  // ---- LDS read offsets (halfwords): frag row r, kunit c = lane>>4:
  //   R = r>>1, s = (4*(r&1)+c) ^ (R&7), off = R*64 + s*8
  const int rhalf = (lane & 15) >> 1;
  const int soff = ((4 * (lane & 1) + (lane >> 4)) ^ rhalf) * 8;
  const int aoff = (wm * 64 + rhalf) * 64 + soff;   // + m*512
  const int boff = (wn * 32 + rhalf) * 64 + soff;   // + n*512

  for (int t = 0; t < NT; ++t) {
    if (t < NT - 2)      asm volatile("s_waitcnt vmcnt(8)" ::: "memory");
    else if (t < NT - 1) asm volatile("s_waitcnt vmcnt(4)" ::: "memory");
    else                 asm volatile("s_waitcnt vmcnt(0)" ::: "memory");
    __builtin_amdgcn_s_barrier();
    if (t + 3 < NT) STAGE(t + 3);
    const ushort* La = &lds[t & 3][0][0];
    const ushort* Lb = &lds[t & 3][1][0];
    bf8v af0 = *(const bf8v*)(La + aoff);
    bf8v bf[4];
    #pragma unroll
    for (int n = 0; n < 4; ++n) bf[n] = *(const bf8v*)(Lb + boff + n * 512);
    bf8v af[8];
    af[0] = af0;
    #pragma unroll
    for (int m = 1; m < 8; ++m) af[m] = *(const bf8v*)(La + aoff + m * 512);
    __builtin_amdgcn_s_setprio(1);
    #pragma unroll
    for (int m = 0; m < 8; ++m)
      #pragma unroll
      for (int n = 0; n < 4; ++n)
        acc[m][n] = __builtin_amdgcn_mfma_f32_16x16x32_bf16(af[m], bf[n], acc[m][n], 0, 0, 0);
    __builtin_amdgcn_s_setprio(0);
  }
#undef STAGE

  const int colbase = bn + wn * 64 + (lane & 15);
  const long rowb0 = bm + wm * 128 + ((lane >> 4) * 4);
  const float* biasp = (EPI == 4) ? bias + ((bm >> 13) << 9) : bias;
  #pragma unroll
  for (int m = 0; m < 8; ++m) {
    #pragma unroll
    for (int j = 0; j < 4; ++j) {
      const long row = rowb0 + m * 16 + j;
      #pragma unroll
      for (int n = 0; n < 4; ++n) {
        const int col = colbase + n * 16;
        float v = acc[m][n][j] + biasp[col];
        const long idx = row * (long)ldc + col;
        if constexpr (EPI == 0) {
          ((ushort*)Out)[idx] = f2bf(v);
        } else if constexpr (EPI == 2) {
          ((ushort*)Out)[idx] = f2bf(gelu_f(v));
        } else if constexpr (EPI == 3) {
          ((float*)Out)[idx] = (resid[idx] + gelu_f(v)) * mask[row];
        } else {
          ((float*)Out)[idx] = v + resid[idx];
        }
      }
    }
  }
}

// ---------------- stage 1 pooling: softmax over N of Q·q_alpha, weighted Q sum
__global__ __launch_bounds__(1024) void pool_stage1(
    const ushort* __restrict__ Q, const float* __restrict__ qa,
    const float* __restrict__ mask, float* __restrict__ gq)
{
  __shared__ float sl[8192];
  __shared__ float red[16];
  __shared__ float sca[64];
  __shared__ float bcast;
  const int bh = blockIdx.x;
  const int b = bh >> 3, h = bh & 7;
  const int tid = threadIdx.x, lane = tid & 63, wv = tid >> 6;
  if (tid < 64) sca[tid] = qa[h * 64 + tid];
  __syncthreads();
  const float scale = 0.125f;
  float lmax = -INFINITY;
  for (int n = tid; n < 8192; n += 1024) {
    const ushort* qp = Q + ((long)(b * 8192 + n) * 1536 + h * 64);
    float dot = 0.f;
    #pragma unroll
    for (int c = 0; c < 8; ++c) {
      s8v v = *(const s8v*)(qp + c * 8);
      #pragma unroll
      for (int j = 0; j < 8; ++j) dot += bf2f((ushort)v[j]) * sca[c * 8 + j];
    }
    float lg = dot * scale;
    if (mask[b * 8192 + n] == 0.f) lg = -INFINITY;
    sl[n] = lg;
    lmax = fmaxf(lmax, lg);
  }
  lmax = wave_max_f(lmax);
  if (lane == 0) red[wv] = lmax;
  __syncthreads();
  if (tid < 64) {
    float v = (lane < 16) ? red[lane] : -INFINITY;
    v = wave_max_f(v);
    if (lane == 0) bcast = v;
  }
  __syncthreads();
  const float gmax = bcast;
  float lsum = 0.f;
  for (int n = tid; n < 8192; n += 1024) {
    float e = __expf(sl[n] - gmax);
    sl[n] = e;
    lsum += e;
  }
  lsum = wave_sum_f(lsum);
  __syncthreads();
  if (lane == 0) red[wv] = lsum;
  __syncthreads();
  if (tid < 64) {
    float v = (lane < 16) ? red[lane] : 0.f;
    v = wave_sum_f(v);
    if (lane == 0) bcast = v;
  }
  __syncthreads();
  const float S = bcast;
  float acc = 0.f;
  for (int n = wv; n < 8192; n += 16) {
    acc += sl[n] * bf2f(Q[(long)(b * 8192 + n) * 1536 + h * 64 + lane]);
  }
  __syncthreads();
  sl[wv * 64 + lane] = acc;
  __syncthreads();
  if (tid < 64) {
    float t = 0.f;
    #pragma unroll
    for (int w2 = 0; w2 < 16; ++w2) t += sl[w2 * 64 + tid];
    gq[bh * 64 + tid] = t / S;
  }
}

// ---------------- stage 2 pooling: softmax over N of (K*gq)·k_beta, weighted V sum
__global__ __launch_bounds__(1024) void pool_stage2(
    const ushort* __restrict__ Km, const ushort* __restrict__ Vm,
    const float* __restrict__ kb, const float* __restrict__ gq,
    const float* __restrict__ mask, float* __restrict__ gv)
{
  __shared__ float sl[8192];
  __shared__ float red[16];
  __shared__ float wvec[64];
  __shared__ float bcast;
  const int bh = blockIdx.x;
  const int b = bh >> 3, h = bh & 7;
  const int tid = threadIdx.x, lane = tid & 63, wv = tid >> 6;
  if (tid < 64) wvec[tid] = gq[bh * 64 + tid] * kb[h * 64 + tid];
  __syncthreads();
  const float scale = 0.125f;
  float lmax = -INFINITY;
  for (int n = tid; n < 8192; n += 1024) {
    const ushort* kp = Km + ((long)(b * 8192 + n) * 1536 + h * 64);
    float dot = 0.f;
    #pragma unroll
    for (int c = 0; c < 8; ++c) {
      s8v v = *(const s8v*)(kp + c * 8);
      #pragma unroll
      for (int j = 0; j < 8; ++j) dot += bf2f((ushort)v[j]) * wvec[c * 8 + j];
    }
    float lg = dot * scale;
    if (mask[b * 8192 + n] == 0.f) lg = -INFINITY;
    sl[n] = lg;
    lmax = fmaxf(lmax, lg);
  }
  lmax = wave_max_f(lmax);
  if (lane == 0) red[wv] = lmax;
  __syncthreads();
  if (tid < 64) {
    float v = (lane < 16) ? red[lane] : -INFINITY;
    v = wave_max_f(v);
    if (lane == 0) bcast = v;
  }
  __syncthreads();
  const float gmax = bcast;
  float lsum = 0.f;
  for (int n = tid; n < 8192; n += 1024) {
    float e = __expf(sl[n] - gmax);
    sl[n] = e;
    lsum += e;
  }
  lsum = wave_sum_f(lsum);
  __syncthreads();
  if (lane == 0) red[wv] = lsum;
  __syncthreads();
  if (tid < 64) {
    float v = (lane < 16) ? red[lane] : 0.f;
    v = wave_sum_f(v);
    if (lane == 0) bcast = v;
  }
  __syncthreads();
  const float S = bcast;
  float acc = 0.f;
  for (int n = wv; n < 8192; n += 16) {
    acc += sl[n] * bf2f(Vm[(long)(b * 8192 + n) * 1536 + h * 64 + lane]);
  }
  __syncthreads();
  sl[wv * 64 + lane] = acc;
  __syncthreads();
  if (tid < 64) {
    float t = 0.f;
    #pragma unroll
    for (int w2 = 0; w2 < 16; ++w2) t += sl[w2 * 64 + tid];
    gv[bh * 64 + tid] = t / S;
  }
}

// ---------------- host ----------------
extern "C" void kernel_launch(void* const* d_in, const int* in_sizes, int n_in,
                              void* d_out, int out_size, void* d_ws, size_t ws_size,
                              hipStream_t stream) {
  const float* x    = (const float*)d_in[0];
  const float* mask = (const float*)d_in[1];
  const float* Wq   = (const float*)d_in[2];
  const float* bq   = (const float*)d_in[3];
  const float* Wk   = (const float*)d_in[4];
  const float* bk   = (const float*)d_in[5];
  const float* Wv   = (const float*)d_in[6];
  const float* bv   = (const float*)d_in[7];
  const float* qa   = (const float*)d_in[8];
  const float* kb   = (const float*)d_in[9];
  const float* Wo   = (const float*)d_in[10];
  const float* bo   = (const float*)d_in[11];
  const float* g0   = (const float*)d_in[12];
  const float* be0  = (const float*)d_in[13];
  const float* g1   = (const float*)d_in[14];
  const float* be1  = (const float*)d_in[15];
  const float* W1   = (const float*)d_in[16];
  const float* b1   = (const float*)d_in[17];
  const float* W2   = (const float*)d_in[18];
  const float* b2   = (const float*)d_in[19];
  float* out = (float*)d_out;

  const int M = 65536;          // B*N
  char* ws = (char*)d_ws;
  const size_t MB = 1024 * 1024;
  ushort* XN  = (ushort*)(ws);            // [0,64) ln outs / W1 input
  ushort* QKV = (ushort*)(ws + 64 * MB);  // [64,256) bf16 [M,1536]
  ushort* H1  = (ushort*)(ws + 64 * MB);  // [64,320) bf16 [M,2048] (after QKV dead)
  float*  X1  = (float*)(ws + 320 * MB);  // [320,448) f32 [M,512]
  char* small = ws + 448 * MB;
  float*  GQ  = (float*)(small);
  float*  GV  = (float*)(small + 16 * 1024);
  float*  BO2 = (float*)(small + 32 * 1024);
  float*  BQKV= (float*)(small + 48 * 1024);
  ushort* WQKVB = (ushort*)(small + 64 * 1024);
  ushort* WOB = WQKVB + 3 * 262144;
  ushort* W1B = WOB + 262144;
  ushort* W2B = W1B + 1048576;

  cvt_f32_bf16<<<256, 256, 0, stream>>>(Wq, WQKVB, 262144);
  cvt_f32_bf16<<<256, 256, 0, stream>>>(Wk, WQKVB + 262144, 262144);
  cvt_f32_bf16<<<256, 256, 0, stream>>>(Wv, WQKVB + 524288, 262144);
  cvt_f32_bf16<<<256, 256, 0, stream>>>(Wo, WOB, 262144);
  cvt_f32_bf16<<<1024, 256, 0, stream>>>(W1, W1B, 1048576);
  cvt_f32_bf16<<<1024, 256, 0, stream>>>(W2, W2B, 1048576);
  concat_bias<<<6, 256, 0, stream>>>(bq, bk, bv, BQKV);

  // LN0 (+mask)
  ln_rows<<<M / 4, 256, 0, stream>>>(x, g0, be0, mask, XN);

  // fused QKV GEMM: [M,512] @ [1536,512]^T -> [M,1536]
  gemm256<0><<<6 * (M / BM), 512, 0, stream>>>(XN, 512, WQKVB, 512, BQKV, nullptr, nullptr, QKV, 1536, 512, 6);

  // pooling
  pool_stage1<<<64, 1024, 0, stream>>>(QKV, qa, mask, GQ);
  pool_stage2<<<64, 1024, 0, stream>>>(QKV + 512, QKV + 1024, kb, GQ, mask, GV);

  // fold global_v into Wo bias
  bias_gv<<<dim3(8, 2), 256, 0, stream>>>(GV, Wo, bo, BO2);

  // Wo GEMM + batched bias + residual -> X1 (f32); A = Q columns of QKV
  gemm256<4><<<2 * (M / BM), 512, 0, stream>>>(QKV, 1536, WOB, 512, BO2, x, nullptr, X1, 512, 512, 2);

  // LN1 -> XN (bf16)
  ln_rows<<<M / 4, 256, 0, stream>>>(X1, g1, be1, nullptr, XN);

  // MLP
  gemm256<2><<<8 * (M / BM), 512, 0, stream>>>(XN, 512, W1B, 512, b1, nullptr, nullptr, H1, 2048, 512, 8);
  gemm256<3><<<2 * (M / BM), 512, 0, stream>>>(H1, 2048, W2B, 2048, b2, X1, mask, out, 512, 2048, 2);
}

// Round 4
// 1063.681 us; speedup vs baseline: 1.1174x; 1.0639x over previous
//
#include <hip/hip_runtime.h>
#include <hip/hip_bf16.h>
#include <math.h>

typedef short s8v __attribute__((ext_vector_type(8)));
typedef short s4v __attribute__((ext_vector_type(4)));
typedef __bf16 bf8v __attribute__((ext_vector_type(8)));
typedef float f4v __attribute__((ext_vector_type(4)));

#define GLOBAL_AS __attribute__((address_space(1)))
#define LDS_AS __attribute__((address_space(3)))

static __device__ __forceinline__ float bf2f(ushort u) {
  return __builtin_bit_cast(float, (unsigned int)u << 16);
}
static __device__ __forceinline__ ushort f2bf(float f) {
  unsigned int u = __builtin_bit_cast(unsigned int, f);
  u += 0x7FFFu + ((u >> 16) & 1u);
  return (ushort)(u >> 16);
}
// fast tanh-gelu with hardware rcp (no slow IEEE division)
static __device__ __forceinline__ float gelu_f(float v) {
  float t = v * v;
  float u = v * (0.0356774081f * t + 0.7978845608f);
  float e = __expf(-2.0f * u);
  return v * __builtin_amdgcn_rcpf(1.0f + e);
}
static __device__ __forceinline__ float wave_max_f(float v) {
  #pragma unroll
  for (int o = 32; o >= 1; o >>= 1) v = fmaxf(v, __shfl_xor(v, o));
  return v;
}
static __device__ __forceinline__ float wave_sum_f(float v) {
  #pragma unroll
  for (int o = 32; o >= 1; o >>= 1) v += __shfl_xor(v, o);
  return v;
}
static __device__ __forceinline__ void gload16(const ushort* g, const ushort* l) {
  __builtin_amdgcn_global_load_lds(
      (const GLOBAL_AS unsigned int*)g,
      (LDS_AS unsigned int*)l, 16, 0, 0);
}

// ---------------- weight fp32 -> bf16 convert ----------------
__global__ void cvt_f32_bf16(const float* __restrict__ in, ushort* __restrict__ out, int n) {
  int i = (blockIdx.x * 256 + threadIdx.x) * 4;
  if (i >= n) return;
  float4 v = *(const float4*)(in + i);
  s4v o;
  o[0] = (short)f2bf(v.x); o[1] = (short)f2bf(v.y);
  o[2] = (short)f2bf(v.z); o[3] = (short)f2bf(v.w);
  *(s4v*)(out + i) = o;
}

// ---------------- concat qkv biases ----------------
__global__ void concat_bias(const float* __restrict__ bq, const float* __restrict__ bk,
                            const float* __restrict__ bv, float* __restrict__ o) {
  int i = blockIdx.x * 256 + threadIdx.x;
  if (i < 512) o[i] = bq[i];
  else if (i < 1024) o[i] = bk[i - 512];
  else if (i < 1536) o[i] = bv[i - 1024];
}

// ---------------- batched Wo bias: bo2[b][n] = bo[n] + gv[b]·Wo[n,:] -------
__global__ __launch_bounds__(256) void bias_gv(
    const float* __restrict__ gv, const float* __restrict__ Wo,
    const float* __restrict__ bo, float* __restrict__ bo2) {
  const int b = blockIdx.x;
  const int n = blockIdx.y * 256 + threadIdx.x;
  const float* g = gv + b * 512;
  const float* w = Wo + (long)n * 512;
  float acc = 0.f;
  for (int d = 0; d < 512; d += 4) {
    float4 wv4 = *(const float4*)(w + d);
    acc += g[d] * wv4.x + g[d + 1] * wv4.y + g[d + 2] * wv4.z + g[d + 3] * wv4.w;
  }
  bo2[b * 512 + n] = bo[n] + acc;
}

// ---------------- LayerNorm over D=512, one wave per row ----------------
__global__ __launch_bounds__(256) void ln_rows(
    const float* __restrict__ x, const float* __restrict__ gam,
    const float* __restrict__ bet, const float* __restrict__ mask,
    ushort* __restrict__ out)
{
  const int tid = threadIdx.x, lane = tid & 63, wv = tid >> 6;
  const long row = (long)blockIdx.x * 4 + wv;
  const float* xp = x + row * 512 + lane * 8;
  float4 a = *(const float4*)xp;
  float4 b = *(const float4*)(xp + 4);
  float s = a.x + a.y + a.z + a.w + b.x + b.y + b.z + b.w;
  float q = a.x*a.x + a.y*a.y + a.z*a.z + a.w*a.w
          + b.x*b.x + b.y*b.y + b.z*b.z + b.w*b.w;
  s = wave_sum_f(s); q = wave_sum_f(q);
  float m = s * (1.f / 512.f);
  float var = q * (1.f / 512.f) - m * m;
  float r = rsqrtf(var + 1e-5f);
  float mk = mask ? mask[row] : 1.f;
  const float* gp = gam + lane * 8;
  const float* bp = bet + lane * 8;
  float4 g0 = *(const float4*)gp, g1 = *(const float4*)(gp + 4);
  float4 c0 = *(const float4*)bp, c1 = *(const float4*)(bp + 4);
  s8v o;
  o[0] = (short)f2bf(((a.x - m) * r * g0.x + c0.x) * mk);
  o[1] = (short)f2bf(((a.y - m) * r * g0.y + c0.y) * mk);
  o[2] = (short)f2bf(((a.z - m) * r * g0.z + c0.z) * mk);
  o[3] = (short)f2bf(((a.w - m) * r * g0.w + c0.w) * mk);
  o[4] = (short)f2bf(((b.x - m) * r * g1.x + c1.x) * mk);
  o[5] = (short)f2bf(((b.y - m) * r * g1.y + c1.y) * mk);
  o[6] = (short)f2bf(((b.z - m) * r * g1.z + c1.z) * mk);
  o[7] = (short)f2bf(((b.w - m) * r * g1.w + c1.w) * mk);
  *(s8v*)(out + row * 512 + lane * 8) = o;
}

// ======== 256x256 8-phase pipelined bf16 GEMM: C = A[M,K] @ W[N,K]^T =======
// 8 waves (2M x 4N), per-wave C 128x64. BK=64, double-buffered LDS (128KB).
// 4 phases per K-tile; per phase: {ds_read frag subtile; issue 2 gload_lds
// line stages for tile T+1; counted vmcnt; raw s_barrier; setprio(1);
// 16 MFMA quadrant; setprio(0)}. vmcnt never drains to 0 in steady state.
// LDS layout: one source row per 128B LDS row, 8 slots of 16B, slot =
// kunit ^ (row&7) (involution pre-applied to global source per-lane).
// Lines (8KB, 64 rows): stage order per tile: B0,B1 | B2,B3 | A0,A2 | A1,A3.
// EPI 0: bf16 = v+bias ; 2: bf16 = gelu(v+bias) ;
// 3: f32 = (resid+gelu(v+bias))*mask[row] ; 4: f32 = v+bias_b[row>>13]+resid
#define MFMA_(d,a,b) d = __builtin_amdgcn_mfma_f32_16x16x32_bf16(a, b, d, 0, 0, 0)

template<int EPI, int LDA, int NN, int KK>
__global__ __launch_bounds__(512, 2) void gemm256(
    const ushort* __restrict__ A, const ushort* __restrict__ W,
    const float* __restrict__ bias, const float* __restrict__ resid,
    const float* __restrict__ mask, void* __restrict__ Out)
{
  constexpr int NBX = NN / 256;
  constexpr int NT = KK / 64;
  __shared__ __align__(16) ushort lds[2][2][16384];  // [buf][A|B][256*64]
  const int tid = threadIdx.x;
  const int lane = tid & 63;
  const int w = tid >> 6;
  const int wm = w >> 2, wn = w & 3;

  // chunked bijective XCD swizzle (nwg % 8 == 0 for all launches)
  const int nwg = gridDim.x;
  const int cpx = nwg >> 3;
  const int wg = (blockIdx.x & 7) * cpx + (blockIdx.x >> 3);
  const int bx = wg % NBX, by = wg / NBX;
  const long bm = (long)by * 256;
  const int bn = bx * 256;

  // staging: thread covers (line l): row l*64 + (tid>>3), kunit (tid&7)^((tid>>3)&7)
  const int srow = tid >> 3;
  const int sku = (tid & 7) ^ (srow & 7);
  const ushort* aln[4];
  const ushort* bln[4];
  #pragma unroll
  for (int l = 0; l < 4; ++l) {
    aln[l] = A + (bm + l * 64 + srow) * (long)LDA + sku * 8;
    bln[l] = W + (long)(bn + l * 64 + srow) * KK + sku * 8;
  }

#define STG_A(bf_, l_, Tt) gload16(aln[l_] + (Tt) * 64, &lds[bf_][0][(l_) * 4096 + w * 512])
#define STG_B(bf_, l_, Tt) gload16(bln[l_] + (Tt) * 64, &lds[bf_][1][(l_) * 4096 + w * 512])

  // prologue: tile 0 -> buf 0, in steady-state order
  STG_B(0, 0, 0); STG_B(0, 1, 0);
  STG_B(0, 2, 0); STG_B(0, 3, 0);
  STG_A(0, 0, 0); STG_A(0, 2, 0);
  STG_A(0, 1, 0); STG_A(0, 3, 0);

  f4v acc[8][4] = {};

  // frag read offsets (ushort units); row&7 == lane&7 for all frags
  const int s0 = ((lane >> 4) ^ (lane & 7)) * 8;
  const int s1 = ((4 + (lane >> 4)) ^ (lane & 7)) * 8;
  const int ar = (wm * 128 + (lane & 15)) * 64;   // + mi*1024
  const int br = (wn * 64 + (lane & 15)) * 64;    // + n*1024

  asm volatile("s_waitcnt vmcnt(2)" ::: "memory");
  asm volatile("s_barrier" ::: "memory");

  for (int T = 0; T < NT; ++T) {
    const int buf = T & 1, nb = buf ^ 1;
    const ushort* LA = &lds[buf][0][0];
    const ushort* LB = &lds[buf][1][0];
    const bool st = (T + 1 < NT);
    bf8v aR[8], bR[8];
    // ---------- q0: reads A m0-3, B n0-1; stage B-L0,L1; MFMA m0-3 x n0-1
    #pragma unroll
    for (int m = 0; m < 4; ++m) {
      aR[2 * m]     = *(const bf8v*)(LA + ar + m * 1024 + s0);
      aR[2 * m + 1] = *(const bf8v*)(LA + ar + m * 1024 + s1);
    }
    #pragma unroll
    for (int n = 0; n < 2; ++n) {
      bR[2 * n]     = *(const bf8v*)(LB + br + n * 1024 + s0);
      bR[2 * n + 1] = *(const bf8v*)(LB + br + n * 1024 + s1);
    }
    if (st) { STG_B(nb, 0, T + 1); STG_B(nb, 1, T + 1); }
    asm volatile("s_barrier" ::: "memory");
    __builtin_amdgcn_s_setprio(1);
    #pragma unroll
    for (int m = 0; m < 4; ++m)
      #pragma unroll
      for (int n = 0; n < 2; ++n) {
        MFMA_(acc[m][n], aR[2 * m], bR[2 * n]);
        MFMA_(acc[m][n], aR[2 * m + 1], bR[2 * n + 1]);
      }
    __builtin_amdgcn_s_setprio(0);
    // ---------- q1: reads B n2-3; stage B-L2,L3; vmcnt; MFMA m0-3 x n2-3
    #pragma unroll
    for (int n = 2; n < 4; ++n) {
      bR[2 * n]     = *(const bf8v*)(LB + br + n * 1024 + s0);
      bR[2 * n + 1] = *(const bf8v*)(LB + br + n * 1024 + s1);
    }
    if (st) { STG_B(nb, 2, T + 1); STG_B(nb, 3, T + 1); }
    if (st) asm volatile("s_waitcnt vmcnt(4)" ::: "memory");
    else    asm volatile("s_waitcnt vmcnt(0)" ::: "memory");
    asm volatile("s_barrier" ::: "memory");
    __builtin_amdgcn_s_setprio(1);
    #pragma unroll
    for (int m = 0; m < 4; ++m)
      #pragma unroll
      for (int n = 2; n < 4; ++n) {
        MFMA_(acc[m][n], aR[2 * m], bR[2 * n]);
        MFMA_(acc[m][n], aR[2 * m + 1], bR[2 * n + 1]);
      }
    __builtin_amdgcn_s_setprio(0);
    // ---------- q2: reads A m4-7; stage A-L0,L2; MFMA m4-7 x n0-1
    #pragma unroll
    for (int m = 0; m < 4; ++m) {
      aR[2 * m]     = *(const bf8v*)(LA + ar + (m + 4) * 1024 + s0);
      aR[2 * m + 1] = *(const bf8v*)(LA + ar + (m + 4) * 1024 + s1);
    }
    if (st) { STG_A(nb, 0, T + 1); STG_A(nb, 2, T + 1); }
    asm volatile("s_barrier" ::: "memory");
    __builtin_amdgcn_s_setprio(1);
    #pragma unroll
    for (int m = 0; m < 4; ++m)
      #pragma unroll
      for (int n = 0; n < 2; ++n) {
        MFMA_(acc[m + 4][n], aR[2 * m], bR[2 * n]);
        MFMA_(acc[m + 4][n], aR[2 * m + 1], bR[2 * n + 1]);
      }
    __builtin_amdgcn_s_setprio(0);
    // ---------- q3: stage A-L1,L3; vmcnt(2); MFMA m4-7 x n2-3
    if (st) { STG_A(nb, 1, T + 1); STG_A(nb, 3, T + 1); }
    asm volatile("s_waitcnt vmcnt(2)" ::: "memory");
    asm volatile("s_barrier" ::: "memory");
    __builtin_amdgcn_s_setprio(1);
    #pragma unroll
    for (int m = 0; m < 4; ++m)
      #pragma unroll
      for (int n = 2; n < 4; ++n) {
        MFMA_(acc[m + 4][n], aR[2 * m], bR[2 * n]);
        MFMA_(acc[m + 4][n], aR[2 * m + 1], bR[2 * n + 1]);
      }
    __builtin_amdgcn_s_setprio(0);
  }
#undef STG_A
#undef STG_B

  // ---------------- epilogue ----------------
  const int colbase = bn + wn * 64 + (lane & 15);
  const long rowb0 = bm + wm * 128 + ((lane >> 4) * 4);
  const float* biasp = (EPI == 4) ? bias + ((bm >> 13) << 9) : bias;
  #pragma unroll
  for (int m = 0; m < 8; ++m) {
    #pragma unroll
    for (int j = 0; j < 4; ++j) {
      const long row = rowb0 + m * 16 + j;
      #pragma unroll
      for (int n = 0; n < 4; ++n) {
        const int col = colbase + n * 16;
        float v = acc[m][n][j] + biasp[col];
        const long idx = row * (long)NN + col;
        if constexpr (EPI == 0) {
          ((ushort*)Out)[idx] = f2bf(v);
        } else if constexpr (EPI == 2) {
          ((ushort*)Out)[idx] = f2bf(gelu_f(v));
        } else if constexpr (EPI == 3) {
          ((float*)Out)[idx] = (resid[idx] + gelu_f(v)) * mask[row];
        } else {
          ((float*)Out)[idx] = v + resid[idx];
        }
      }
    }
  }
}

// ---------------- stage 1 pooling: softmax over N of Q·q_alpha, weighted Q sum
__global__ __launch_bounds__(1024) void pool_stage1(
    const ushort* __restrict__ Q, const float* __restrict__ qa,
    const float* __restrict__ mask, float* __restrict__ gq)
{
  __shared__ float sl[8192];
  __shared__ float red[16];
  __shared__ float sca[64];
  __shared__ float bcast;
  const int bh = blockIdx.x;
  const int b = bh >> 3, h = bh & 7;
  const int tid = threadIdx.x, lane = tid & 63, wv = tid >> 6;
  if (tid < 64) sca[tid] = qa[h * 64 + tid];
  __syncthreads();
  const float scale = 0.125f;
  float lmax = -INFINITY;
  for (int n = tid; n < 8192; n += 1024) {
    const ushort* qp = Q + ((long)(b * 8192 + n) * 1536 + h * 64);
    float dot = 0.f;
    #pragma unroll
    for (int c = 0; c < 8; ++c) {
      s8v v = *(const s8v*)(qp + c * 8);
      #pragma unroll
      for (int j = 0; j < 8; ++j) dot += bf2f((ushort)v[j]) * sca[c * 8 + j];
    }
    float lg = dot * scale;
    if (mask[b * 8192 + n] == 0.f) lg = -INFINITY;
    sl[n] = lg;
    lmax = fmaxf(lmax, lg);
  }
  lmax = wave_max_f(lmax);
  if (lane == 0) red[wv] = lmax;
  __syncthreads();
  if (tid < 64) {
    float v = (lane < 16) ? red[lane] : -INFINITY;
    v = wave_max_f(v);
    if (lane == 0) bcast = v;
  }
  __syncthreads();
  const float gmax = bcast;
  float lsum = 0.f;
  for (int n = tid; n < 8192; n += 1024) {
    float e = __expf(sl[n] - gmax);
    sl[n] = e;
    lsum += e;
  }
  lsum = wave_sum_f(lsum);
  __syncthreads();
  if (lane == 0) red[wv] = lsum;
  __syncthreads();
  if (tid < 64) {
    float v = (lane < 16) ? red[lane] : 0.f;
    v = wave_sum_f(v);
    if (lane == 0) bcast = v;
  }
  __syncthreads();
  const float S = bcast;
  float acc = 0.f;
  for (int n = wv; n < 8192; n += 16) {
    acc += sl[n] * bf2f(Q[(long)(b * 8192 + n) * 1536 + h * 64 + lane]);
  }
  __syncthreads();
  sl[wv * 64 + lane] = acc;
  __syncthreads();
  if (tid < 64) {
    float t = 0.f;
    #pragma unroll
    for (int w2 = 0; w2 < 16; ++w2) t += sl[w2 * 64 + tid];
    gq[bh * 64 + tid] = t / S;
  }
}

// ---------------- stage 2 pooling: softmax over N of (K*gq)·k_beta, weighted V sum
__global__ __launch_bounds__(1024) void pool_stage2(
    const ushort* __restrict__ Km, const ushort* __restrict__ Vm,
    const float* __restrict__ kb, const float* __restrict__ gq,
    const float* __restrict__ mask, float* __restrict__ gv)
{
  __shared__ float sl[8192];
  __shared__ float red[16];
  __shared__ float wvec[64];
  __shared__ float bcast;
  const int bh = blockIdx.x;
  const int b = bh >> 3, h = bh & 7;
  const int tid = threadIdx.x, lane = tid & 63, wv = tid >> 6;
  if (tid < 64) wvec[tid] = gq[bh * 64 + tid] * kb[h * 64 + tid];
  __syncthreads();
  const float scale = 0.125f;
  float lmax = -INFINITY;
  for (int n = tid; n < 8192; n += 1024) {
    const ushort* kp = Km + ((long)(b * 8192 + n) * 1536 + h * 64);
    float dot = 0.f;
    #pragma unroll
    for (int c = 0; c < 8; ++c) {
      s8v v = *(const s8v*)(kp + c * 8);
      #pragma unroll
      for (int j = 0; j < 8; ++j) dot += bf2f((ushort)v[j]) * wvec[c * 8 + j];
    }
    float lg = dot * scale;
    if (mask[b * 8192 + n] == 0.f) lg = -INFINITY;
    sl[n] = lg;
    lmax = fmaxf(lmax, lg);
  }
  lmax = wave_max_f(lmax);
  if (lane == 0) red[wv] = lmax;
  __syncthreads();
  if (tid < 64) {
    float v = (lane < 16) ? red[lane] : -INFINITY;
    v = wave_max_f(v);
    if (lane == 0) bcast = v;
  }
  __syncthreads();
  const float gmax = bcast;
  float lsum = 0.f;
  for (int n = tid; n < 8192; n += 1024) {
    float e = __expf(sl[n] - gmax);
    sl[n] = e;
    lsum += e;
  }
  lsum = wave_sum_f(lsum);
  __syncthreads();
  if (lane == 0) red[wv] = lsum;
  __syncthreads();
  if (tid < 64) {
    float v = (lane < 16) ? red[lane] : 0.f;
    v = wave_sum_f(v);
    if (lane == 0) bcast = v;
  }
  __syncthreads();
  const float S = bcast;
  float acc = 0.f;
  for (int n = wv; n < 8192; n += 16) {
    acc += sl[n] * bf2f(Vm[(long)(b * 8192 + n) * 1536 + h * 64 + lane]);
  }
  __syncthreads();
  sl[wv * 64 + lane] = acc;
  __syncthreads();
  if (tid < 64) {
    float t = 0.f;
    #pragma unroll
    for (int w2 = 0; w2 < 16; ++w2) t += sl[w2 * 64 + tid];
    gv[bh * 64 + tid] = t / S;
  }
}

// ---------------- host ----------------
extern "C" void kernel_launch(void* const* d_in, const int* in_sizes, int n_in,
                              void* d_out, int out_size, void* d_ws, size_t ws_size,
                              hipStream_t stream) {
  const float* x    = (const float*)d_in[0];
  const float* mask = (const float*)d_in[1];
  const float* Wq   = (const float*)d_in[2];
  const float* bq   = (const float*)d_in[3];
  const float* Wk   = (const float*)d_in[4];
  const float* bk   = (const float*)d_in[5];
  const float* Wv   = (const float*)d_in[6];
  const float* bv   = (const float*)d_in[7];
  const float* qa   = (const float*)d_in[8];
  const float* kb   = (const float*)d_in[9];
  const float* Wo   = (const float*)d_in[10];
  const float* bo   = (const float*)d_in[11];
  const float* g0   = (const float*)d_in[12];
  const float* be0  = (const float*)d_in[13];
  const float* g1   = (const float*)d_in[14];
  const float* be1  = (const float*)d_in[15];
  const float* W1   = (const float*)d_in[16];
  const float* b1   = (const float*)d_in[17];
  const float* W2   = (const float*)d_in[18];
  const float* b2   = (const float*)d_in[19];
  float* out = (float*)d_out;

  const int M = 65536;          // B*N
  char* ws = (char*)d_ws;
  const size_t MB = 1024 * 1024;
  ushort* XN  = (ushort*)(ws);            // [0,64) ln outs / W1 input
  ushort* QKV = (ushort*)(ws + 64 * MB);  // [64,256) bf16 [M,1536]
  ushort* H1  = (ushort*)(ws + 64 * MB);  // [64,320) bf16 [M,2048] (after QKV dead)
  float*  X1  = (float*)(ws + 320 * MB);  // [320,448) f32 [M,512]
  char* small = ws + 448 * MB;
  float*  GQ  = (float*)(small);
  float*  GV  = (float*)(small + 16 * 1024);
  float*  BO2 = (float*)(small + 32 * 1024);
  float*  BQKV= (float*)(small + 48 * 1024);
  ushort* WQKVB = (ushort*)(small + 64 * 1024);
  ushort* WOB = WQKVB + 3 * 262144;
  ushort* W1B = WOB + 262144;
  ushort* W2B = W1B + 1048576;

  cvt_f32_bf16<<<256, 256, 0, stream>>>(Wq, WQKVB, 262144);
  cvt_f32_bf16<<<256, 256, 0, stream>>>(Wk, WQKVB + 262144, 262144);
  cvt_f32_bf16<<<256, 256, 0, stream>>>(Wv, WQKVB + 524288, 262144);
  cvt_f32_bf16<<<256, 256, 0, stream>>>(Wo, WOB, 262144);
  cvt_f32_bf16<<<1024, 256, 0, stream>>>(W1, W1B, 1048576);
  cvt_f32_bf16<<<1024, 256, 0, stream>>>(W2, W2B, 1048576);
  concat_bias<<<6, 256, 0, stream>>>(bq, bk, bv, BQKV);

  // LN0 (+mask)
  ln_rows<<<M / 4, 256, 0, stream>>>(x, g0, be0, mask, XN);

  // fused QKV GEMM: [M,512] @ [1536,512]^T -> [M,1536]
  gemm256<0, 512, 1536, 512><<<6 * (M / 256), 512, 0, stream>>>(
      XN, WQKVB, BQKV, nullptr, nullptr, QKV);

  // pooling (Q at col 0, K at 512, V at 1024; row stride 1536)
  pool_stage1<<<64, 1024, 0, stream>>>(QKV, qa, mask, GQ);
  pool_stage2<<<64, 1024, 0, stream>>>(QKV + 512, QKV + 1024, kb, GQ, mask, GV);

  // fold global_v into Wo bias
  bias_gv<<<dim3(8, 2), 256, 0, stream>>>(GV, Wo, bo, BO2);

  // Wo GEMM + batched bias + residual -> X1 (f32); A = Q columns of QKV
  gemm256<4, 1536, 512, 512><<<2 * (M / 256), 512, 0, stream>>>(
      QKV, WOB, BO2, x, nullptr, X1);

  // LN1 -> XN (bf16)
  ln_rows<<<M / 4, 256, 0, stream>>>(X1, g1, be1, nullptr, XN);

  // MLP
  gemm256<2, 512, 2048, 512><<<8 * (M / 256), 512, 0, stream>>>(
      XN, W1B, b1, nullptr, nullptr, H1);
  gemm256<3, 2048, 512, 2048><<<2 * (M / 256), 512, 0, stream>>>(
      H1, W2B, b2, X1, mask, out);
}

// Round 5
// 703.135 us; speedup vs baseline: 1.6904x; 1.5128x over previous
//
#include <hip/hip_runtime.h>
#include <hip/hip_bf16.h>
#include <math.h>

typedef short s8v __attribute__((ext_vector_type(8)));
typedef short s4v __attribute__((ext_vector_type(4)));
typedef __bf16 bf8v __attribute__((ext_vector_type(8)));
typedef float f4v __attribute__((ext_vector_type(4)));

#define GLOBAL_AS __attribute__((address_space(1)))
#define LDS_AS __attribute__((address_space(3)))

static __device__ __forceinline__ float bf2f(ushort u) {
  return __builtin_bit_cast(float, (unsigned int)u << 16);
}
static __device__ __forceinline__ ushort f2bf(float f) {
  unsigned int u = __builtin_bit_cast(unsigned int, f);
  u += 0x7FFFu + ((u >> 16) & 1u);
  return (ushort)(u >> 16);
}
// fast tanh-gelu with hardware rcp
static __device__ __forceinline__ float gelu_f(float v) {
  float t = v * v;
  float u = v * (0.0356774081f * t + 0.7978845608f);
  float e = __expf(-2.0f * u);
  return v * __builtin_amdgcn_rcpf(1.0f + e);
}
static __device__ __forceinline__ float wave_max_f(float v) {
  #pragma unroll
  for (int o = 32; o >= 1; o >>= 1) v = fmaxf(v, __shfl_xor(v, o));
  return v;
}
static __device__ __forceinline__ float wave_sum_f(float v) {
  #pragma unroll
  for (int o = 32; o >= 1; o >>= 1) v += __shfl_xor(v, o);
  return v;
}
static __device__ __forceinline__ void gload16(const ushort* g, const ushort* l) {
  __builtin_amdgcn_global_load_lds(
      (const GLOBAL_AS unsigned int*)g,
      (LDS_AS unsigned int*)l, 16, 0, 0);
}

// ---------------- weight fp32 -> bf16 convert ----------------
__global__ void cvt_f32_bf16(const float* __restrict__ in, ushort* __restrict__ out, int n) {
  int i = (blockIdx.x * 256 + threadIdx.x) * 4;
  if (i >= n) return;
  float4 v = *(const float4*)(in + i);
  s4v o;
  o[0] = (short)f2bf(v.x); o[1] = (short)f2bf(v.y);
  o[2] = (short)f2bf(v.z); o[3] = (short)f2bf(v.w);
  *(s4v*)(out + i) = o;
}

// ---------------- 512x512 f32 transpose ----------------
__global__ __launch_bounds__(256) void transpose512(
    const float* __restrict__ in, float* __restrict__ out) {
  __shared__ float t[32][33];
  const int bx = blockIdx.x & 15, by = blockIdx.x >> 4;
  const int tx = threadIdx.x & 31, ty = threadIdx.x >> 5;
  #pragma unroll
  for (int i = 0; i < 4; ++i)
    t[ty + i * 8][tx] = in[(long)(by * 32 + ty + i * 8) * 512 + bx * 32 + tx];
  __syncthreads();
  #pragma unroll
  for (int i = 0; i < 4; ++i)
    out[(long)(bx * 32 + ty + i * 8) * 512 + by * 32 + tx] = t[tx][ty + i * 8];
}

// ---------------- Wqo = Wo @ Wq  (f32 inputs, bf16 out) ----------------
__global__ __launch_bounds__(256) void wqo_kernel(
    const float* __restrict__ Wo, const float* __restrict__ Wq,
    ushort* __restrict__ WqoB)
{
  __shared__ float lO[64][33];
  __shared__ float lQ[32][65];
  const int t = threadIdx.x;
  const int bi = (blockIdx.x & 7) * 64, bj = (blockIdx.x >> 3) * 64;
  float acc[16] = {};
  for (int k0 = 0; k0 < 512; k0 += 32) {
    __syncthreads();
    {
      const int r = t >> 2, c = (t & 3) * 8;
      #pragma unroll
      for (int j = 0; j < 8; ++j) lO[r][c + j] = Wo[(long)(bi + r) * 512 + k0 + c + j];
      const int r2 = t >> 3, c2 = (t & 7) * 8;
      #pragma unroll
      for (int j = 0; j < 8; ++j) lQ[r2][c2 + j] = Wq[(long)(k0 + r2) * 512 + bj + c2 + j];
    }
    __syncthreads();
    const int j = t & 63, ig = t >> 6;
    for (int kk = 0; kk < 32; ++kk) {
      float q = lQ[kk][j];
      #pragma unroll
      for (int ii = 0; ii < 16; ++ii) acc[ii] += lO[ig * 16 + ii][kk] * q;
    }
  }
  const int j = t & 63, ig = t >> 6;
  #pragma unroll
  for (int ii = 0; ii < 16; ++ii)
    WqoB[(long)(bi + ig * 16 + ii) * 512 + bj + j] = f2bf(acc[ii]);
}

// ---------------- wa[h,k] = sum_d qa[h,d] Wq[h*64+d,k]; ca[h] = qa_h . bq_h
__global__ __launch_bounds__(256) void wa_kernel(
    const float* __restrict__ qa, const float* __restrict__ Wq,
    const float* __restrict__ bqv, ushort* __restrict__ waB, float* __restrict__ ca)
{
  __shared__ float ql[64];
  const int h = blockIdx.x;   // 0..15 (8..15 pad)
  const int t = threadIdx.x;
  if (h >= 8) {
    waB[h * 512 + t] = 0; waB[h * 512 + 256 + t] = 0;
    if (t == 0) ca[h] = 0.f;
    return;
  }
  if (t < 64) ql[t] = qa[h * 64 + t];
  __syncthreads();
  #pragma unroll
  for (int half = 0; half < 2; ++half) {
    const int k = half * 256 + t;
    float s = 0;
    for (int dd = 0; dd < 64; ++dd) s += ql[dd] * Wq[(long)(h * 64 + dd) * 512 + k];
    waB[h * 512 + k] = f2bf(s);
  }
  if (t == 0) {
    float s = 0;
    for (int dd = 0; dd < 64; ++dd) s += ql[dd] * bqv[h * 64 + dd];
    ca[h] = s;
  }
}

// ---------------- LayerNorm over D=512, one wave per row ----------------
__global__ __launch_bounds__(256) void ln_rows(
    const float* __restrict__ x, const float* __restrict__ gam,
    const float* __restrict__ bet, const float* __restrict__ mask,
    ushort* __restrict__ out)
{
  const int tid = threadIdx.x, lane = tid & 63, wv = tid >> 6;
  const long row = (long)blockIdx.x * 4 + wv;
  const float* xp = x + row * 512 + lane * 8;
  float4 a = *(const float4*)xp;
  float4 b = *(const float4*)(xp + 4);
  float s = a.x + a.y + a.z + a.w + b.x + b.y + b.z + b.w;
  float q = a.x*a.x + a.y*a.y + a.z*a.z + a.w*a.w
          + b.x*b.x + b.y*b.y + b.z*b.z + b.w*b.w;
  s = wave_sum_f(s); q = wave_sum_f(q);
  float m = s * (1.f / 512.f);
  float var = q * (1.f / 512.f) - m * m;
  float r = rsqrtf(var + 1e-5f);
  float mk = mask ? mask[row] : 1.f;
  const float* gp = gam + lane * 8;
  const float* bp = bet + lane * 8;
  float4 g0 = *(const float4*)gp, g1 = *(const float4*)(gp + 4);
  float4 c0 = *(const float4*)bp, c1 = *(const float4*)(bp + 4);
  s8v o;
  o[0] = (short)f2bf(((a.x - m) * r * g0.x + c0.x) * mk);
  o[1] = (short)f2bf(((a.y - m) * r * g0.y + c0.y) * mk);
  o[2] = (short)f2bf(((a.z - m) * r * g0.z + c0.z) * mk);
  o[3] = (short)f2bf(((a.w - m) * r * g0.w + c0.w) * mk);
  o[4] = (short)f2bf(((b.x - m) * r * g1.x + c1.x) * mk);
  o[5] = (short)f2bf(((b.y - m) * r * g1.y + c1.y) * mk);
  o[6] = (short)f2bf(((b.z - m) * r * g1.z + c1.z) * mk);
  o[7] = (short)f2bf(((b.w - m) * r * g1.w + c1.w) * mk);
  *(s8v*)(out + row * 512 + lane * 8) = o;
}

// ---------------- logits via MFMA: L[bh][n] = (xn . Wl[b?,h] + c[b?,h])/8 ---
// Wl: [.][16][512] bf16 (rows 8..15 zero). BS = b-stride (ushorts), CS = cvec b-stride.
template<int BS, int CS>
__global__ __launch_bounds__(256) void logits_k(
    const ushort* __restrict__ XN, const ushort* __restrict__ Wl,
    const float* __restrict__ cvec, const float* __restrict__ mask,
    float* __restrict__ outL)
{
  __shared__ ushort lw[16 * 512];
  const int tid = threadIdx.x, lane = tid & 63, wv = tid >> 6;
  const long r0 = (long)blockIdx.x * 64;
  const int b = (int)(r0 >> 13);
  #pragma unroll
  for (int i = 0; i < 4; ++i) {
    const int u = tid + i * 256;
    const int h2 = u >> 6, uu = u & 63;
    s8v v = *(const s8v*)(Wl + (long)b * BS + h2 * 512 + uu * 8);
    *(s8v*)(lw + h2 * 512 + (uu ^ (h2 & 7)) * 8) = v;
  }
  __syncthreads();
  const int h = lane & 15, q = lane >> 4;
  const long rw = r0 + wv * 16;
  const ushort* ap = XN + (rw + (lane & 15)) * 512 + q * 8;
  f4v acc = {};
  #pragma unroll
  for (int t = 0; t < 16; ++t) {
    bf8v a = *(const bf8v*)(ap + t * 32);
    bf8v bb = *(const bf8v*)(lw + h * 512 + (((t * 4 + q) ^ (h & 7))) * 8);
    acc = __builtin_amdgcn_mfma_f32_16x16x32_bf16(a, bb, acc, 0, 0, 0);
  }
  const float cv = cvec[b * CS + h];
  #pragma unroll
  for (int j = 0; j < 4; ++j) {
    const long n = rw + q * 4 + j;
    float v = (acc[j] + cv) * 0.125f;
    if (mask[n] == 0.f) v = -1e30f;
    if (h < 8) outL[((long)((b << 3) + h) << 13) + (n & 8191)] = v;
  }
}

// ---------------- softmax over N=8192 per (b,h), in place ----------------
__global__ __launch_bounds__(1024) void softmax_rows(float* __restrict__ L)
{
  __shared__ float red[16];
  __shared__ float bc;
  const int tid = threadIdx.x, lane = tid & 63, wv = tid >> 6;
  float* p = L + ((long)blockIdx.x << 13) + tid * 8;
  float4 v0 = *(float4*)p;
  float4 v1 = *(float4*)(p + 4);
  float m = fmaxf(fmaxf(fmaxf(v0.x, v0.y), fmaxf(v0.z, v0.w)),
                  fmaxf(fmaxf(v1.x, v1.y), fmaxf(v1.z, v1.w)));
  m = wave_max_f(m);
  if (lane == 0) red[wv] = m;
  __syncthreads();
  if (tid < 64) {
    float t = (lane < 16) ? red[lane] : -INFINITY;
    t = wave_max_f(t);
    if (lane == 0) bc = t;
  }
  __syncthreads();
  const float gm = bc;
  v0.x = __expf(v0.x - gm); v0.y = __expf(v0.y - gm);
  v0.z = __expf(v0.z - gm); v0.w = __expf(v0.w - gm);
  v1.x = __expf(v1.x - gm); v1.y = __expf(v1.y - gm);
  v1.z = __expf(v1.z - gm); v1.w = __expf(v1.w - gm);
  float s = v0.x + v0.y + v0.z + v0.w + v1.x + v1.y + v1.z + v1.w;
  s = wave_sum_f(s);
  __syncthreads();
  if (lane == 0) red[wv] = s;
  __syncthreads();
  if (tid < 64) {
    float t = (lane < 16) ? red[lane] : 0.f;
    t = wave_sum_f(t);
    if (lane == 0) bc = t;
  }
  __syncthreads();
  const float inv = 1.0f / bc;
  v0.x *= inv; v0.y *= inv; v0.z *= inv; v0.w *= inv;
  v1.x *= inv; v1.y *= inv; v1.z *= inv; v1.w *= inv;
  *(float4*)p = v0;
  *(float4*)(p + 4) = v1;
}

// ---------------- weighted pool partials: part[b,ch][h][c] = sum w*xn -----
// grid 512 (8 b x 64 chunks of 128 rows), block 256.
__global__ __launch_bounds__(256) void pool_w(
    const ushort* __restrict__ XN, const float* __restrict__ wbuf,
    float* __restrict__ part)
{
  __shared__ float wlds[128][8];
  __shared__ float cmb[4][512];
  const int tid = threadIdx.x;
  const int b = blockIdx.x >> 6, ch = blockIdx.x & 63;
  const long g0 = ((long)b << 13) + ch * 128;
  if (tid < 128) {
    #pragma unroll
    for (int h = 0; h < 8; ++h)
      wlds[tid][h] = wbuf[(((long)(b * 8 + h)) << 13) + ch * 128 + tid];
  }
  __syncthreads();
  const int rg = tid >> 6, c8 = (tid & 63) * 8;
  f4v acc[8][2] = {};
  for (int it = 0; it < 32; ++it) {
    const int r = it * 4 + rg;
    s8v xv = *(const s8v*)(XN + (g0 + r) * 512 + c8);
    float xf[8];
    #pragma unroll
    for (int j = 0; j < 8; ++j) xf[j] = bf2f((ushort)xv[j]);
    #pragma unroll
    for (int h = 0; h < 8; ++h) {
      const float w = wlds[r][h];
      #pragma unroll
      for (int j = 0; j < 8; ++j) acc[h][j >> 2][j & 3] += w * xf[j];
    }
  }
  #pragma unroll
  for (int h = 0; h < 8; ++h) {
    __syncthreads();
    #pragma unroll
    for (int j = 0; j < 8; ++j) cmb[rg][c8 + j] = acc[h][j >> 2][j & 3];
    __syncthreads();
    const int col = tid * 2;
    float s0 = cmb[0][col] + cmb[1][col] + cmb[2][col] + cmb[3][col];
    float s1 = cmb[0][col + 1] + cmb[1][col + 1] + cmb[2][col + 1] + cmb[3][col + 1];
    *(float2*)(part + (((long)blockIdx.x * 8 + h) << 9) + col) = make_float2(s0, s1);
  }
}

// ---------------- combine partials -> px[bh][512] ----------------
__global__ __launch_bounds__(256) void combine_px(
    const float* __restrict__ part, float* __restrict__ px)
{
  const int bh = blockIdx.x;
  const int b = bh >> 3, h = bh & 7;
  const int col = threadIdx.x * 2;
  float s0 = 0.f, s1 = 0.f;
  for (int ch = 0; ch < 64; ++ch) {
    const float* p = part + (((long)((b * 64 + ch) * 8 + h)) << 9) + col;
    s0 += p[0]; s1 += p[1];
  }
  px[(bh << 9) + col] = s0;
  px[(bh << 9) + col + 1] = s1;
}

// ---------------- prep1: gq = px@Wq_h^T + bq_h; wb,cb for beta logits -----
__global__ __launch_bounds__(64) void prep_gq_wb(
    const float* __restrict__ px, const float* __restrict__ WqT,
    const float* __restrict__ bqv, const float* __restrict__ kbv,
    const float* __restrict__ Wk, const float* __restrict__ bkv,
    ushort* __restrict__ wbB, float* __restrict__ cbs)
{
  __shared__ float pxl[512];
  __shared__ float gkb[64];
  const int bh = blockIdx.x, b = bh >> 3, h = bh & 7, d = threadIdx.x;
  #pragma unroll
  for (int i = 0; i < 8; ++i) pxl[d + i * 64] = px[(bh << 9) + d + i * 64];
  __syncthreads();
  float acc = bqv[h * 64 + d];
  for (int c = 0; c < 512; ++c) acc += pxl[c] * WqT[(long)c * 512 + h * 64 + d];
  gkb[d] = acc * kbv[h * 64 + d];
  __syncthreads();
  float s[8] = {};
  for (int dd = 0; dd < 64; ++dd) {
    const float g = gkb[dd];
    const float* wr = Wk + (long)(h * 64 + dd) * 512 + d;
    #pragma unroll
    for (int ki = 0; ki < 8; ++ki) s[ki] += g * wr[ki * 64];
  }
  #pragma unroll
  for (int ki = 0; ki < 8; ++ki)
    wbB[(long)(b * 16 + h) * 512 + d + ki * 64] = f2bf(s[ki]);
  if (d == 0) {
    float t = 0.f;
    for (int dd = 0; dd < 64; ++dd) t += gkb[dd] * bkv[h * 64 + dd];
    cbs[b * 16 + h] = t;
  }
  if (h == 0) {
    #pragma unroll
    for (int hp = 8; hp < 16; ++hp)
      for (int k = d; k < 512; k += 64) wbB[(long)(b * 16 + hp) * 512 + k] = 0;
    if (d < 8) cbs[b * 16 + 8 + d] = 0.f;
  }
}

// ---------------- prep2: gvb[b,k] = pv@Wv_h^T + bv + bq ----------------
__global__ __launch_bounds__(64) void prep_gv(
    const float* __restrict__ pv, const float* __restrict__ WvT,
    const float* __restrict__ bvv, const float* __restrict__ bqv,
    float* __restrict__ gvb)
{
  __shared__ float pxl[512];
  const int bh = blockIdx.x, b = bh >> 3, h = bh & 7, d = threadIdx.x;
  #pragma unroll
  for (int i = 0; i < 8; ++i) pxl[d + i * 64] = pv[(bh << 9) + d + i * 64];
  __syncthreads();
  float acc = bvv[h * 64 + d] + bqv[h * 64 + d];
  for (int c = 0; c < 512; ++c) acc += pxl[c] * WvT[(long)c * 512 + h * 64 + d];
  gvb[b * 512 + h * 64 + d] = acc;
}

// ---------------- BO2[b][n] = bo[n] + gvb[b]·Wo[n,:] ----------------
__global__ __launch_bounds__(256) void bias_gv(
    const float* __restrict__ gv, const float* __restrict__ Wo,
    const float* __restrict__ bo, float* __restrict__ bo2) {
  const int b = blockIdx.x;
  const int n = blockIdx.y * 256 + threadIdx.x;
  const float* g = gv + b * 512;
  const float* w = Wo + (long)n * 512;
  float acc = 0.f;
  for (int d = 0; d < 512; d += 4) {
    float4 wv4 = *(const float4*)(w + d);
    acc += g[d] * wv4.x + g[d + 1] * wv4.y + g[d + 2] * wv4.z + g[d + 3] * wv4.w;
  }
  bo2[b * 512 + n] = bo[n] + acc;
}

// ======== 256x256 8-phase pipelined bf16 GEMM: C = A[M,K] @ W[N,K]^T =======
#define MFMA_(d,a,b) d = __builtin_amdgcn_mfma_f32_16x16x32_bf16(a, b, d, 0, 0, 0)

template<int EPI, int LDA, int NN, int KK>
__global__ __launch_bounds__(512, 2) void gemm256(
    const ushort* __restrict__ A, const ushort* __restrict__ W,
    const float* __restrict__ bias, const float* __restrict__ resid,
    const float* __restrict__ mask, void* __restrict__ Out)
{
  constexpr int NBX = NN / 256;
  constexpr int NT = KK / 64;
  __shared__ __align__(16) ushort lds[2][2][16384];
  const int tid = threadIdx.x;
  const int lane = tid & 63;
  const int w = tid >> 6;
  const int wm = w >> 2, wn = w & 3;

  const int nwg = gridDim.x;
  const int cpx = nwg >> 3;
  const int wg = (blockIdx.x & 7) * cpx + (blockIdx.x >> 3);
  const int bx = wg % NBX, by = wg / NBX;
  const long bm = (long)by * 256;
  const int bn = bx * 256;

  const int srow = tid >> 3;
  const int sku = (tid & 7) ^ (srow & 7);
  const ushort* aln[4];
  const ushort* bln[4];
  #pragma unroll
  for (int l = 0; l < 4; ++l) {
    aln[l] = A + (bm + l * 64 + srow) * (long)LDA + sku * 8;
    bln[l] = W + (long)(bn + l * 64 + srow) * KK + sku * 8;
  }

#define STG_A(bf_, l_, Tt) gload16(aln[l_] + (Tt) * 64, &lds[bf_][0][(l_) * 4096 + w * 512])
#define STG_B(bf_, l_, Tt) gload16(bln[l_] + (Tt) * 64, &lds[bf_][1][(l_) * 4096 + w * 512])

  STG_B(0, 0, 0); STG_B(0, 1, 0);
  STG_B(0, 2, 0); STG_B(0, 3, 0);
  STG_A(0, 0, 0); STG_A(0, 2, 0);
  STG_A(0, 1, 0); STG_A(0, 3, 0);

  f4v acc[8][4] = {};

  const int s0 = ((lane >> 4) ^ (lane & 7)) * 8;
  const int s1 = ((4 + (lane >> 4)) ^ (lane & 7)) * 8;
  const int ar = (wm * 128 + (lane & 15)) * 64;
  const int br = (wn * 64 + (lane & 15)) * 64;

  asm volatile("s_waitcnt vmcnt(2)" ::: "memory");
  asm volatile("s_barrier" ::: "memory");

  for (int T = 0; T < NT; ++T) {
    const int buf = T & 1, nb = buf ^ 1;
    const ushort* LA = &lds[buf][0][0];
    const ushort* LB = &lds[buf][1][0];
    const bool st = (T + 1 < NT);
    bf8v aR[8], bR[8];
    #pragma unroll
    for (int m = 0; m < 4; ++m) {
      aR[2 * m]     = *(const bf8v*)(LA + ar + m * 1024 + s0);
      aR[2 * m + 1] = *(const bf8v*)(LA + ar + m * 1024 + s1);
    }
    #pragma unroll
    for (int n = 0; n < 2; ++n) {
      bR[2 * n]     = *(const bf8v*)(LB + br + n * 1024 + s0);
      bR[2 * n + 1] = *(const bf8v*)(LB + br + n * 1024 + s1);
    }
    if (st) { STG_B(nb, 0, T + 1); STG_B(nb, 1, T + 1); }
    asm volatile("s_barrier" ::: "memory");
    __builtin_amdgcn_s_setprio(1);
    #pragma unroll
    for (int m = 0; m < 4; ++m)
      #pragma unroll
      for (int n = 0; n < 2; ++n) {
        MFMA_(acc[m][n], aR[2 * m], bR[2 * n]);
        MFMA_(acc[m][n], aR[2 * m + 1], bR[2 * n + 1]);
      }
    __builtin_amdgcn_s_setprio(0);
    #pragma unroll
    for (int n = 2; n < 4; ++n) {
      bR[2 * n]     = *(const bf8v*)(LB + br + n * 1024 + s0);
      bR[2 * n + 1] = *(const bf8v*)(LB + br + n * 1024 + s1);
    }
    if (st) { STG_B(nb, 2, T + 1); STG_B(nb, 3, T + 1); }
    if (st) asm volatile("s_waitcnt vmcnt(4)" ::: "memory");
    else    asm volatile("s_waitcnt vmcnt(0)" ::: "memory");
    asm volatile("s_barrier" ::: "memory");
    __builtin_amdgcn_s_setprio(1);
    #pragma unroll
    for (int m = 0; m < 4; ++m)
      #pragma unroll
      for (int n = 2; n < 4; ++n) {
        MFMA_(acc[m][n], aR[2 * m], bR[2 * n]);
        MFMA_(acc[m][n], aR[2 * m + 1], bR[2 * n + 1]);
      }
    __builtin_amdgcn_s_setprio(0);
    #pragma unroll
    for (int m = 0; m < 4; ++m) {
      aR[2 * m]     = *(const bf8v*)(LA + ar + (m + 4) * 1024 + s0);
      aR[2 * m + 1] = *(const bf8v*)(LA + ar + (m + 4) * 1024 + s1);
    }
    if (st) { STG_A(nb, 0, T + 1); STG_A(nb, 2, T + 1); }
    asm volatile("s_barrier" ::: "memory");
    __builtin_amdgcn_s_setprio(1);
    #pragma unroll
    for (int m = 0; m < 4; ++m)
      #pragma unroll
      for (int n = 0; n < 2; ++n) {
        MFMA_(acc[m + 4][n], aR[2 * m], bR[2 * n]);
        MFMA_(acc[m + 4][n], aR[2 * m + 1], bR[2 * n + 1]);
      }
    __builtin_amdgcn_s_setprio(0);
    if (st) { STG_A(nb, 1, T + 1); STG_A(nb, 3, T + 1); }
    asm volatile("s_waitcnt vmcnt(2)" ::: "memory");
    asm volatile("s_barrier" ::: "memory");
    __builtin_amdgcn_s_setprio(1);
    #pragma unroll
    for (int m = 0; m < 4; ++m)
      #pragma unroll
      for (int n = 2; n < 4; ++n) {
        MFMA_(acc[m + 4][n], aR[2 * m], bR[2 * n]);
        MFMA_(acc[m + 4][n], aR[2 * m + 1], bR[2 * n + 1]);
      }
    __builtin_amdgcn_s_setprio(0);
  }
#undef STG_A
#undef STG_B

  const int colbase = bn + wn * 64 + (lane & 15);
  const long rowb0 = bm + wm * 128 + ((lane >> 4) * 4);
  const float* biasp = (EPI == 4) ? bias + ((bm >> 13) << 9) : bias;
  #pragma unroll
  for (int m = 0; m < 8; ++m) {
    #pragma unroll
    for (int j = 0; j < 4; ++j) {
      const long row = rowb0 + m * 16 + j;
      #pragma unroll
      for (int n = 0; n < 4; ++n) {
        const int col = colbase + n * 16;
        float v = acc[m][n][j] + biasp[col];
        const long idx = row * (long)NN + col;
        if constexpr (EPI == 0) {
          ((ushort*)Out)[idx] = f2bf(v);
        } else if constexpr (EPI == 2) {
          ((ushort*)Out)[idx] = f2bf(gelu_f(v));
        } else if constexpr (EPI == 3) {
          ((float*)Out)[idx] = (resid[idx] + gelu_f(v)) * mask[row];
        } else {
          ((float*)Out)[idx] = v + resid[idx];
        }
      }
    }
  }
}

// ---------------- host ----------------
extern "C" void kernel_launch(void* const* d_in, const int* in_sizes, int n_in,
                              void* d_out, int out_size, void* d_ws, size_t ws_size,
                              hipStream_t stream) {
  const float* x    = (const float*)d_in[0];
  const float* mask = (const float*)d_in[1];
  const float* Wq   = (const float*)d_in[2];
  const float* bq   = (const float*)d_in[3];
  const float* Wk   = (const float*)d_in[4];
  const float* bk   = (const float*)d_in[5];
  const float* Wv   = (const float*)d_in[6];
  const float* bv   = (const float*)d_in[7];
  const float* qa   = (const float*)d_in[8];
  const float* kb   = (const float*)d_in[9];
  const float* Wo   = (const float*)d_in[10];
  const float* bo   = (const float*)d_in[11];
  const float* g0   = (const float*)d_in[12];
  const float* be0  = (const float*)d_in[13];
  const float* g1   = (const float*)d_in[14];
  const float* be1  = (const float*)d_in[15];
  const float* W1   = (const float*)d_in[16];
  const float* b1   = (const float*)d_in[17];
  const float* W2   = (const float*)d_in[18];
  const float* b2   = (const float*)d_in[19];
  float* out = (float*)d_out;

  const int M = 65536;          // B*N
  char* ws = (char*)d_ws;
  const size_t MB = 1024 * 1024;
  // [0,64)    XN bf16 (ln0 out; later ln1 out)
  // [64,192)  X1 f32
  // [192,448) H1 bf16 (W1 out). Transients AL/BL/part live here BEFORE W1.
  ushort* XN  = (ushort*)(ws);
  float*  X1  = (float*)(ws + 64 * MB);
  ushort* H1  = (ushort*)(ws + 192 * MB);
  float*  AL  = (float*)(ws + 192 * MB);          // [64][8192] f32, 2MB
  float*  BL  = (float*)(ws + 194 * MB);          // 2MB
  float*  PART= (float*)(ws + 196 * MB);          // 8MB
  char* base = ws + 448 * MB;
  ushort* W1B  = (ushort*)(base);                 // 2MB
  ushort* W2B  = (ushort*)(base + 2 * MB);        // 2MB
  ushort* WqoB = (ushort*)(base + 4 * MB);        // 512KB
  float*  WqT  = (float*)(base + 4 * MB + 512 * 1024);   // 1MB
  float*  WvT  = (float*)(base + 5 * MB + 512 * 1024);   // 1MB
  ushort* waB  = (ushort*)(base + 6 * MB + 512 * 1024);  // 16KB
  ushort* wbB  = (ushort*)(base + 6 * MB + 528 * 1024);  // 128KB
  float*  ca   = (float*)(base + 6 * MB + 656 * 1024);   // 4KB slot
  float*  cbs  = (float*)(base + 6 * MB + 660 * 1024);   // 4KB slot
  float*  PX   = (float*)(base + 6 * MB + 664 * 1024);   // 128KB
  float*  PV   = (float*)(base + 6 * MB + 792 * 1024);   // 128KB
  float*  GVB  = (float*)(base + 6 * MB + 920 * 1024);   // 16KB
  float*  BO2  = (float*)(base + 6 * MB + 936 * 1024);   // 16KB

  // ---- weight precompute ----
  cvt_f32_bf16<<<1024, 256, 0, stream>>>(W1, W1B, 1048576);
  cvt_f32_bf16<<<1024, 256, 0, stream>>>(W2, W2B, 1048576);
  wqo_kernel<<<64, 256, 0, stream>>>(Wo, Wq, WqoB);
  wa_kernel<<<16, 256, 0, stream>>>(qa, Wq, bq, waB, ca);
  transpose512<<<256, 256, 0, stream>>>(Wq, WqT);
  transpose512<<<256, 256, 0, stream>>>(Wv, WvT);

  // ---- LN0 (+mask) ----
  ln_rows<<<M / 4, 256, 0, stream>>>(x, g0, be0, mask, XN);

  // ---- stage 1: alpha logits -> softmax -> pooled x -> gq/wb ----
  logits_k<0, 0><<<1024, 256, 0, stream>>>(XN, waB, ca, mask, AL);
  softmax_rows<<<64, 1024, 0, stream>>>(AL);
  pool_w<<<512, 256, 0, stream>>>(XN, AL, PART);
  combine_px<<<64, 256, 0, stream>>>(PART, PX);
  prep_gq_wb<<<64, 64, 0, stream>>>(PX, WqT, bq, kb, Wk, bk, wbB, cbs);

  // ---- stage 2: beta logits -> softmax -> pooled x -> gv ----
  logits_k<8192, 16><<<1024, 256, 0, stream>>>(XN, wbB, cbs, mask, BL);
  softmax_rows<<<64, 1024, 0, stream>>>(BL);
  pool_w<<<512, 256, 0, stream>>>(XN, BL, PART);
  combine_px<<<64, 256, 0, stream>>>(PART, PV);
  prep_gv<<<64, 64, 0, stream>>>(PV, WvT, bv, bq, GVB);
  bias_gv<<<dim3(8, 2), 256, 0, stream>>>(GVB, Wo, bo, BO2);

  // ---- attention out: X1 = xn @ Wqo^T + BO2[b] + x ----
  gemm256<4, 512, 512, 512><<<2 * (M / 256), 512, 0, stream>>>(
      XN, WqoB, BO2, x, nullptr, X1);

  // ---- LN1 -> XN ----
  ln_rows<<<M / 4, 256, 0, stream>>>(X1, g1, be1, nullptr, XN);

  // ---- MLP ----
  gemm256<2, 512, 2048, 512><<<8 * (M / 256), 512, 0, stream>>>(
      XN, W1B, b1, nullptr, nullptr, H1);
  gemm256<3, 2048, 512, 2048><<<2 * (M / 256), 512, 0, stream>>>(
      H1, W2B, b2, X1, mask, out);
}